// Round 7
// baseline (262.766 us; speedup 1.0000x reference)
//
#include <hip/hip_runtime.h>

// SelfAttention: B=4 S=2048 D=1024 H=16 HD=64, causal, fp32 in/out, bf16 MFMA compute.
// R15->R16: resubmit of the 256^2 8-phase GEMM template (R15 bench died at the
// container level with no kernel-attributable signal; schedule re-audited: vmcnt(6)
// ring proven for prologue/steady/peel, all addresses in bounds, barriers uniform).
// Mainloop: 256x256 tile, BK=64, 512thr/8 waves (2m x 4n), 128KB LDS 2-tile dbuf,
// 8 phases per 2 K-tiles: {ds_read subtile || 1 half-tile glds stage -> barrier ->
// setprio(1) 16xMFMA -> barrier}, counted vmcnt(6) ONLY at phases 4/8 (never 0 in
// steady loop; peel drains vmcnt(0)). 16B-granule XOR swizzle both sides
// (pre-swizzled glds source + swizzled ds_read) -> conflict-free b128 reads.
// XCD swizzle: qkv cpx=48 (384%8==0), out cpx=16 (128%8==0).
// attn/cast/transpose byte-identical to R14 (known-good).

typedef __attribute__((ext_vector_type(8))) short short8_t;
typedef __attribute__((ext_vector_type(4))) short short4_t;
typedef __attribute__((ext_vector_type(4))) float float4_t;

constexpr int Bz = 4, Sq = 2048, Dm = 1024, NH = 16, HD = 64;

#define GLOAD_LDS16(g, l)                                                      \
  __builtin_amdgcn_global_load_lds(                                            \
      (const __attribute__((address_space(1))) unsigned int*)(g),              \
      (__attribute__((address_space(3))) unsigned int*)(l), 16, 0, 0)

__device__ __forceinline__ unsigned short f2bf(float f) {
  unsigned u = __builtin_bit_cast(unsigned, f);
  u += 0x7fffu + ((u >> 16) & 1u);
  return (unsigned short)(u >> 16);
}

__device__ __forceinline__ float exp2_fast(float x) {
#if __has_builtin(__builtin_amdgcn_exp2f)
  return __builtin_amdgcn_exp2f(x);
#else
  return exp2f(x);
#endif
}

__device__ __forceinline__ float m3(float a, float b, float c) {
  return fmaxf(fmaxf(a, b), c);  // clang emits v_max3_f32
}

__global__ __launch_bounds__(256) void cast_x_kernel(const float* __restrict__ x,
                                                     unsigned short* __restrict__ xb) {
  size_t i = (size_t)blockIdx.x * 256 + threadIdx.x;
  float4 v = ((const float4*)x)[i];
  ushort4 o;
  o.x = f2bf(v.x); o.y = f2bf(v.y); o.z = f2bf(v.z); o.w = f2bf(v.w);
  ((ushort4*)xb)[i] = o;
}

// All four W [K=1024][N=1024] fp32 -> WT [N][K] bf16 in one launch. grid (16,16,4).
__global__ __launch_bounds__(256) void transpose_w_kernel(
    const float* __restrict__ Wq, const float* __restrict__ Wk,
    const float* __restrict__ Wv, const float* __restrict__ Wo,
    unsigned short* __restrict__ wqT, unsigned short* __restrict__ wkT,
    unsigned short* __restrict__ wvT, unsigned short* __restrict__ woT) {
  __shared__ float tile[64][65];
  int zz = blockIdx.z;
  const float* W = zz == 0 ? Wq : (zz == 1 ? Wk : (zz == 2 ? Wv : Wo));
  unsigned short* WT = zz == 0 ? wqT : (zz == 1 ? wkT : (zz == 2 ? wvT : woT));
  int n0 = blockIdx.x * 64, k0 = blockIdx.y * 64;
  int tx = threadIdx.x & 63, ty = threadIdx.x >> 6;
#pragma unroll
  for (int i = 0; i < 16; ++i) {
    int r = i * 4 + ty;
    tile[r][tx] = W[(size_t)(k0 + r) * Dm + n0 + tx];
  }
  __syncthreads();
#pragma unroll
  for (int i = 0; i < 16; ++i) {
    int r = i * 4 + ty;
    WT[(size_t)(n0 + r) * Dm + k0 + tx] = f2bf(tile[tx][r]);
  }
}

// ---------------- 256^2 8-phase mainloop ----------------
// LDS layout (shorts): smA/smB each 32768 = 2 buffers x 16384 (one 256x64 K-tile).
// Within a buffer: 2 half-units of 8192 (16KB). A unit h: local row r (0..127)
// holds global m-row (r>>6)*128 + (r&63) + h*64. B unit h: local row r holds
// global n-row ((r&63)>>5)*64 + (r&31) + (r>>6)*128 + h*32.
// 16B-granule XOR swizzle: LDS granule (row, g) holds source granule g ^ (row&7).
#define SBAR do { __builtin_amdgcn_sched_barrier(0); __builtin_amdgcn_s_barrier(); } while (0)
#define VMW(n_) asm volatile("s_waitcnt vmcnt(" #n_ ")" ::: "memory")

#define STG_A(buf_, h_, kt_) do {                                              \
  GLOAD_LDS16(gA + (size_t)(mloc0 + (h_) * 64) * Dm + (kt_) * 64 + csA,        \
              smA + (buf_) * 16384 + (h_) * 8192 + tid * 8);                   \
  GLOAD_LDS16(gA + (size_t)(mloc1 + (h_) * 64) * Dm + (kt_) * 64 + csA,        \
              smA + (buf_) * 16384 + (h_) * 8192 + 4096 + tid * 8);            \
} while (0)
#define STG_B(buf_, h_, kt_) do {                                              \
  GLOAD_LDS16(gB + (size_t)(nloc0 + (h_) * 32) * Dm + (kt_) * 64 + csA,        \
              smB + (buf_) * 16384 + (h_) * 8192 + tid * 8);                   \
  GLOAD_LDS16(gB + (size_t)(nloc1 + (h_) * 32) * Dm + (kt_) * 64 + csA,        \
              smB + (buf_) * 16384 + (h_) * 8192 + 4096 + tid * 8);            \
} while (0)
#define LDA_(buf_, mh_) do {                                                   \
  _Pragma("unroll") for (int i_ = 0; i_ < 4; ++i_) {                           \
    const unsigned short* p_ = smA + (buf_) * 16384 + (mh_) * 8192 + aoff + i_ * 1024; \
    a[i_][0] = *(const short8_t*)(p_ + csw0);                                  \
    a[i_][1] = *(const short8_t*)(p_ + csw1);                                  \
  }                                                                            \
} while (0)
#define LDB_(dst_, buf_, nh_) do {                                             \
  _Pragma("unroll") for (int j_ = 0; j_ < 2; ++j_) {                           \
    const unsigned short* p_ = smB + (buf_) * 16384 + (nh_) * 8192 + boff + j_ * 1024; \
    dst_[j_][0] = *(const short8_t*)(p_ + csw0);                               \
    dst_[j_][1] = *(const short8_t*)(p_ + csw1);                               \
  }                                                                            \
} while (0)
#define MF_(ioff_, breg_, joff_) do {                                          \
  __builtin_amdgcn_s_setprio(1);                                               \
  _Pragma("unroll") for (int i_ = 0; i_ < 4; ++i_)                             \
  _Pragma("unroll") for (int j_ = 0; j_ < 2; ++j_) {                           \
    acc[(ioff_) + i_][(joff_) + j_] = __builtin_amdgcn_mfma_f32_16x16x32_bf16( \
        a[i_][0], breg_[j_][0], acc[(ioff_) + i_][(joff_) + j_], 0, 0, 0);     \
    acc[(ioff_) + i_][(joff_) + j_] = __builtin_amdgcn_mfma_f32_16x16x32_bf16( \
        a[i_][1], breg_[j_][1], acc[(ioff_) + i_][(joff_) + j_], 0, 0, 0);     \
  }                                                                            \
  __builtin_amdgcn_s_setprio(0);                                               \
} while (0)

__device__ __forceinline__ void gemm256_mainloop(
    const unsigned short* __restrict__ A, const unsigned short* __restrict__ BT,
    int m0, int n0, unsigned short* smA, unsigned short* smB,
    float4_t acc[8][4]) {
  const int tid = threadIdx.x;
  const int lane = tid & 63, lr = lane & 15, quad = lane >> 4;
  const int wid = tid >> 6, wm = wid >> 2, wn = wid & 3;
  const int aoff = (wm * 64 + lr) * 64;       // local-row base within a unit (shorts)
  const int boff = (wn * 32 + lr) * 64;
  const int csw0 = (quad ^ (lr & 7)) * 8;     // swizzled read granule, kk=0
  const int csw1 = csw0 ^ 32;                 // kk=1 (granule ^4)
  const int lrow0 = tid >> 3;                 // staging local row, call 0 (0..63)
  const int csA = ((tid & 7) ^ (lrow0 & 7)) * 8;  // pre-swizzled source col (shorts)
  const int mloc0 = lrow0, mloc1 = lrow0 + 128;   // A rows within tile (h adds 64)
  const int nloc0 = (lrow0 >> 5) * 64 + (lrow0 & 31);  // B rows (h adds 32)
  const int nloc1 = nloc0 + 128;
  const unsigned short* gA = A + (size_t)m0 * Dm;
  const unsigned short* gB = BT + (size_t)n0 * Dm;

  short8_t a[4][2], b0[2][2], b1[2][2];

  // prologue: tile0 fully (buf0), tile1 {Ah0,Bh0,Bh1} (buf1); Ah1 of tile1 -> iter0 ph1
  STG_A(0, 0, 0); STG_A(0, 1, 0); STG_B(0, 0, 0); STG_B(0, 1, 0);
  STG_A(1, 0, 1); STG_B(1, 0, 1); STG_B(1, 1, 1);
  VMW(6);  // tile0's 8 glds forced complete; tile1's 3 units may stay in flight
  SBAR;

#pragma unroll 1
  for (int T = 0; T < 7; ++T) {
    const int t1 = 2 * T + 1, t2 = 2 * T + 2, t3 = 2 * T + 3;
    // ---- K-tile 2T (buf0) ----
    LDA_(0, 0); LDB_(b0, 0, 0); STG_A(1, 1, t1); SBAR; MF_(0, b0, 0); SBAR;  // ph1
    LDB_(b1, 0, 1);             STG_A(0, 0, t2); SBAR; MF_(0, b1, 2); SBAR;  // ph2
    LDA_(0, 1);                 STG_B(0, 0, t2); SBAR; MF_(4, b0, 0); SBAR;  // ph3
                                STG_B(0, 1, t2); SBAR; MF_(4, b1, 2); VMW(6); SBAR;  // ph4
    // ---- K-tile 2T+1 (buf1) ----
    LDA_(1, 0); LDB_(b0, 1, 0); STG_A(0, 1, t2); SBAR; MF_(0, b0, 0); SBAR;  // ph5
    LDB_(b1, 1, 1);             STG_A(1, 0, t3); SBAR; MF_(0, b1, 2); SBAR;  // ph6
    LDA_(1, 1);                 STG_B(1, 0, t3); SBAR; MF_(4, b0, 0); SBAR;  // ph7
                                STG_B(1, 1, t3); SBAR; MF_(4, b1, 2); VMW(6); SBAR;  // ph8
  }
  // peeled last iteration: tiles 14 (buf0), 15 (buf1); only ph1 stages (t15.Ah1)
  LDA_(0, 0); LDB_(b0, 0, 0); STG_A(1, 1, 15); SBAR; MF_(0, b0, 0); SBAR;
  LDB_(b1, 0, 1);                              SBAR; MF_(0, b1, 2); SBAR;
  LDA_(0, 1);                                  SBAR; MF_(4, b0, 0); SBAR;
                                               SBAR; MF_(4, b1, 2); VMW(0); SBAR;
  LDA_(1, 0); LDB_(b0, 1, 0);                  SBAR; MF_(0, b0, 0); SBAR;
  LDB_(b1, 1, 1);                              SBAR; MF_(0, b1, 2); SBAR;
  LDA_(1, 1);                                  SBAR; MF_(4, b0, 0); SBAR;
                                               SBAR; MF_(4, b1, 2);
}

// QKV projections, 256^2 tiles. grid 384 linear, XCD swizzle cpx=48.
// Q,K -> [B,H,S,HD]; V -> TRANSPOSED [B,H,HD,S]. Q pre-scaled by 0.125*log2e.
__global__ __launch_bounds__(512, 2) void gemm_qkv_kernel(
    const unsigned short* __restrict__ xb,
    const unsigned short* __restrict__ wqT, const unsigned short* __restrict__ wkT,
    const unsigned short* __restrict__ wvT,
    unsigned short* __restrict__ qb, unsigned short* __restrict__ kb,
    unsigned short* __restrict__ vt) {
  __shared__ unsigned short smA[32768];
  __shared__ unsigned short smB[32768];
  int lin = (int)blockIdx.x;
  int logical = (lin & 7) * 48 + (lin >> 3);
  int bx = logical & 3;
  int by = (logical >> 2) & 31;
  int bz = logical >> 7;
  const unsigned short* WT = bz == 0 ? wqT : (bz == 1 ? wkT : wvT);
  unsigned short* outb = bz == 0 ? qb : (bz == 1 ? kb : vt);
  bool isV = bz == 2;
  float qscale = (bz == 0) ? 0.18033688011112042f : 1.0f;
  int m0 = by * 256, n0 = bx * 256;
  float4_t z = {0.f, 0.f, 0.f, 0.f};
  float4_t acc[8][4];
#pragma unroll
  for (int i = 0; i < 8; ++i)
#pragma unroll
    for (int j = 0; j < 4; ++j) acc[i][j] = z;
  gemm256_mainloop(xb, WT, m0, n0, smA, smB, acc);

  const int lane = threadIdx.x & 63, lr = lane & 15, quad = lane >> 4;
  const int wid = threadIdx.x >> 6, wm = wid >> 2, wn = wid & 3;
  const int mb = m0 + wm * 128 + quad * 4;
  const int nb = n0 + wn * 64 + lr;
  if (isV) {
#pragma unroll
    for (int ai = 0; ai < 8; ++ai)
#pragma unroll
      for (int bj = 0; bj < 4; ++bj) {
        int m = mb + (ai >> 2) * 64 + (ai & 3) * 16;
        int n = nb + (bj >> 1) * 32 + (bj & 1) * 16;
        int b = m >> 11, s = m & (Sq - 1);
        int h = n >> 6, hd = n & (HD - 1);
        ushort4 pk;
        pk.x = f2bf(acc[ai][bj][0]); pk.y = f2bf(acc[ai][bj][1]);
        pk.z = f2bf(acc[ai][bj][2]); pk.w = f2bf(acc[ai][bj][3]);
        *(ushort4*)(outb + (((size_t)b * NH + h) * HD + hd) * Sq + s) = pk;
      }
  } else {
#pragma unroll
    for (int ai = 0; ai < 8; ++ai)
#pragma unroll
      for (int bj = 0; bj < 4; ++bj)
#pragma unroll
        for (int r = 0; r < 4; ++r) {
          int m = mb + (ai >> 2) * 64 + (ai & 3) * 16 + r;
          int n = nb + (bj >> 1) * 32 + (bj & 1) * 16;
          int b = m >> 11, s = m & (Sq - 1);
          int h = n >> 6, hd = n & (HD - 1);
          outb[(((size_t)b * NH + h) * Sq + s) * HD + hd] = f2bf(acc[ai][bj][r] * qscale);
        }
  }
}

// Output projection: ao_bf16 [8192,1024] @ Wo -> fp32. grid 128 linear, cpx=16.
__global__ __launch_bounds__(512, 2) void gemm_out_kernel(
    const unsigned short* __restrict__ ao, const unsigned short* __restrict__ woT,
    float* __restrict__ out) {
  __shared__ unsigned short smA[32768];
  __shared__ unsigned short smB[32768];
  int lin = (int)blockIdx.x;
  int logical = (lin & 7) * 16 + (lin >> 3);
  int bx = logical & 3;
  int by = logical >> 2;
  int m0 = by * 256, n0 = bx * 256;
  float4_t z = {0.f, 0.f, 0.f, 0.f};
  float4_t acc[8][4];
#pragma unroll
  for (int i = 0; i < 8; ++i)
#pragma unroll
    for (int j = 0; j < 4; ++j) acc[i][j] = z;
  gemm256_mainloop(ao, woT, m0, n0, smA, smB, acc);

  const int lane = threadIdx.x & 63, lr = lane & 15, quad = lane >> 4;
  const int wid = threadIdx.x >> 6, wm = wid >> 2, wn = wid & 3;
  const int mb = m0 + wm * 128 + quad * 4;
  const int nb = n0 + wn * 64 + lr;
#pragma unroll
  for (int ai = 0; ai < 8; ++ai)
#pragma unroll
    for (int bj = 0; bj < 4; ++bj)
#pragma unroll
      for (int r = 0; r < 4; ++r) {
        int m = mb + (ai >> 2) * 64 + (ai & 3) * 16 + r;
        int n = nb + (bj >> 1) * 32 + (bj & 1) * 16;
        out[(size_t)m * Dm + n] = acc[ai][bj][r];
      }
}

// Flash attention — grid (B*H, 32), one 64-row q-tile per block, ti = 31 - blockIdx.y.
// Double-buffered K (glds, 16B-granule XOR) and V (reg-staged, 8B-slot XOR ^row&15).
__global__ __launch_bounds__(256) void attn_kernel(
    const unsigned short* __restrict__ qbuf, const unsigned short* __restrict__ kbuf,
    const unsigned short* __restrict__ vtbuf, unsigned short* __restrict__ ao) {
  __shared__ unsigned short lk[2 * 64 * 64];
  __shared__ unsigned short lv[2 * 64 * 64];
  int tid = threadIdx.x;
  int bh = blockIdx.x;
  int ti = 31 - (int)blockIdx.y;
  int wave = tid >> 6, lane = tid & 63;
  int lcol = lane & 15, quad = lane >> 4;
  int lc7 = lcol & 7;
  const unsigned short* Q = qbuf + (size_t)bh * Sq * HD;
  const unsigned short* K = kbuf + (size_t)bh * Sq * HD;
  const unsigned short* Vt = vtbuf + (size_t)bh * HD * Sq;
  int b = bh >> 4, h = bh & 15;
  float4_t z = {0.f, 0.f, 0.f, 0.f};

  // --- K staging map (glds direct, 16B granule g ^= row&7) ---
  const int r0 = tid >> 3;                    // 0..31 (second call: +32)
  const int sgk = (tid & 7) ^ (r0 & 7);       // pre-swizzled source granule
  const unsigned short* kg = K + (size_t)r0 * HD + sgk * 8;  // += 64*HD per tile
  const int kdst = tid * 8;                   // linear dest (shorts)

  // --- V staging map (reg-staged, 8B slot d = w ^ (row&15)) ---
  const int w0 = (tid & 7) * 2;
  const int xa = r0 & 15;
  const int d0 = w0 ^ xa;                     // LDS slot holding content slot w0
  const unsigned short* vsrc = Vt + (size_t)r0 * Sq + w0 * 4;  // += 64 per tile
  const int vdst = r0 * 64 + d0 * 4;          // shorts; partner slot = vdst ^ 4

  // --- swizzled read offsets ---
  const int koff0 = (quad ^ lc7) * 8;
  const int koff1 = ((quad | 4) ^ lc7) * 8;
  int voff[4];
#pragma unroll
  for (int s4 = 0; s4 < 4; ++s4) voff[s4] = ((s4 * 4 + quad) ^ lcol) * 4;

  unsigned short* lkc = lk;
  unsigned short* lkn = lk + 4096;
  unsigned short* lvc = lv;
  unsigned short* lvn = lv + 4096;

  int q0w = ti * 64 + wave * 16;
  int q_global = q0w + lcol;
  short8_t qf0 = *(const short8_t*)(Q + (size_t)(q0w + lcol) * HD + quad * 8);
  short8_t qf1 = *(const short8_t*)(Q + (size_t)(q0w + lcol) * HD + 32 + quad * 8);
  float m_i = -INFINITY, l_i = 0.f;
  float4_t o[4];
#pragma unroll
  for (int f = 0; f < 4; ++f) o[f] = z;

  // --- prologue: stage tile 0 into current buffers ---
  {
    GLOAD_LDS16(kg, lkc + kdst);
    GLOAD_LDS16(kg + (size_t)32 * HD, lkc + 2048 + kdst);
    short4_t a0 = *(const short4_t*)(vsrc);
    short4_t a1 = *(const short4_t*)(vsrc + 4);
    short4_t b0 = *(const short4_t*)(vsrc + (size_t)32 * Sq);
    short4_t b1 = *(const short4_t*)(vsrc + (size_t)32 * Sq + 4);
    *(short4_t*)(lvc + vdst) = a0;
    *(short4_t*)(lvc + (vdst ^ 4)) = a1;
    *(short4_t*)(lvc + vdst + 2048) = b0;
    *(short4_t*)(lvc + (vdst ^ 4) + 2048) = b1;
  }
  __syncthreads();

  int nkt = ti + 1;
  for (int kt = 0; kt < nkt; ++kt) {
    bool has_next = (kt + 1 < nkt);
    short4_t a0, a1, b0, b1;
    if (has_next) {
      const unsigned short* vs = vsrc + (size_t)(kt + 1) * 64;
      a0 = *(const short4_t*)(vs);
      a1 = *(const short4_t*)(vs + 4);
      b0 = *(const short4_t*)(vs + (size_t)32 * Sq);
      b1 = *(const short4_t*)(vs + (size_t)32 * Sq + 4);
      const unsigned short* kgn = kg + (size_t)(kt + 1) * 64 * HD;
      GLOAD_LDS16(kgn, lkn + kdst);
      GLOAD_LDS16(kgn + (size_t)32 * HD, lkn + 2048 + kdst);
    }

    // --- QK^T from lkc ---
    float s[16];
#pragma unroll
    for (int s4 = 0; s4 < 4; ++s4) {
      const unsigned short* kr = lkc + (s4 * 16 + lcol) * 64;
      short8_t kf0 = *(const short8_t*)(kr + koff0);
      short8_t kf1 = *(const short8_t*)(kr + koff1);
      float4_t st = z;
      st = __builtin_amdgcn_mfma_f32_16x16x32_bf16(kf0, qf0, st, 0, 0, 0);
      st = __builtin_amdgcn_mfma_f32_16x16x32_bf16(kf1, qf1, st, 0, 0, 0);
#pragma unroll
      for (int r = 0; r < 4; ++r) s[s4 * 4 + r] = st[r];
    }
    if (kt == ti) {  // diagonal tile: causal mask (uniform branch)
      int key0 = kt * 64;
#pragma unroll
      for (int s4 = 0; s4 < 4; ++s4)
#pragma unroll
        for (int r = 0; r < 4; ++r)
          if (key0 + s4 * 16 + quad * 4 + r > q_global) s[s4 * 4 + r] = -INFINITY;
    }

    // max3-tree reduction over 16 values
    float ta = m3(s[0], s[1], s[2]);
    float tb = m3(s[3], s[4], s[5]);
    float tc = m3(s[6], s[7], s[8]);
    float td = m3(s[9], s[10], s[11]);
    float te = m3(s[12], s[13], s[14]);
    float tmax = m3(ta, tb, tc);
    tmax = m3(tmax, td, te);
    tmax = fmaxf(tmax, s[15]);
    tmax = fmaxf(tmax, __shfl_xor(tmax, 16, 64));
    tmax = fmaxf(tmax, __shfl_xor(tmax, 32, 64));

    // T13 defer-max (log2 domain, THR=8 -> P bounded by 256)
    if (__any(tmax > m_i + 8.f)) {
      float m_new = fmaxf(m_i, tmax);
      float alpha = exp2_fast(m_i - m_new);
      l_i *= alpha;
      m_i = m_new;
      float at[4];
#pragma unroll
      for (int r = 0; r < 4; ++r) at[r] = __shfl(alpha, quad * 4 + r, 64);
#pragma unroll
      for (int f = 0; f < 4; ++f)
#pragma unroll
        for (int r = 0; r < 4; ++r) o[f][r] *= at[r];
    }

    float psum = 0.f;
    short4_t pf[4];
#pragma unroll
    for (int s4 = 0; s4 < 4; ++s4) {
      float p0 = exp2_fast(s[s4 * 4 + 0] - m_i);
      float p1 = exp2_fast(s[s4 * 4 + 1] - m_i);
      float p2 = exp2_fast(s[s4 * 4 + 2] - m_i);
      float p3 = exp2_fast(s[s4 * 4 + 3] - m_i);
      psum += (p0 + p1) + (p2 + p3);
      unsigned lo, hi;
      asm("v_cvt_pk_bf16_f32 %0, %1, %2" : "=v"(lo) : "v"(p0), "v"(p1));
      asm("v_cvt_pk_bf16_f32 %0, %1, %2" : "=v"(hi) : "v"(p2), "v"(p3));
      uint2 packed;
      packed.x = lo;
      packed.y = hi;
      pf[s4] = __builtin_bit_cast(short4_t, packed);
    }
    psum += __shfl_xor(psum, 16, 64);
    psum += __shfl_xor(psum, 32, 64);
    l_i += psum;

    // --- write next-tile V into alternate buffer (vmcnt wait was hidden above) ---
    if (has_next) {
      *(short4_t*)(lvn + vdst) = a0;
      *(short4_t*)(lvn + (vdst ^ 4)) = a1;
      *(short4_t*)(lvn + vdst + 2048) = b0;
      *(short4_t*)(lvn + (vdst ^ 4) + 2048) = b1;
    }

    // --- PV from lvc (conflict-free swizzled b64 reads) ---
#pragma unroll
    for (int f = 0; f < 4; ++f) {
      const unsigned short* vr = lvc + (f * 16 + lcol) * 64;
#pragma unroll
      for (int s4 = 0; s4 < 4; ++s4) {
        short4_t vf = *(const short4_t*)(vr + voff[s4]);
        o[f] = __builtin_amdgcn_mfma_f32_16x16x16bf16_1k(pf[s4], vf, o[f], 0, 0, 0);
      }
    }

    __syncthreads();  // drains K glds (vmcnt0) + V ds_writes; buffers swap
    unsigned short* t;
    t = lkc; lkc = lkn; lkn = t;
    t = lvc; lvc = lvn; lvn = t;
  }

  float lt[4];
#pragma unroll
  for (int r = 0; r < 4; ++r) lt[r] = 1.f / __shfl(l_i, quad * 4 + r, 64);
#pragma unroll
  for (int f = 0; f < 4; ++f)
#pragma unroll
    for (int r = 0; r < 4; ++r) {
      int q = q0w + quad * 4 + r;
      int hd = f * 16 + lcol;
      ao[((size_t)b * Sq + q) * (NH * HD) + h * HD + hd] = f2bf(o[f][r] * lt[r]);
    }
}

extern "C" void kernel_launch(void* const* d_in, const int* in_sizes, int n_in,
                              void* d_out, int out_size, void* d_ws, size_t ws_size,
                              hipStream_t stream) {
  const float* x = (const float*)d_in[0];
  const float* Wq = (const float*)d_in[1];
  const float* Wk = (const float*)d_in[2];
  const float* Wv = (const float*)d_in[3];
  const float* Wo = (const float*)d_in[4];
  float* out = (float*)d_out;

  char* ws = (char*)d_ws;
  size_t off = 0;
  auto carve = [&](size_t bytes) {
    void* p = ws + off;
    off += (bytes + 255) & ~(size_t)255;
    return p;
  };
  const size_t xe = (size_t)Bz * Sq * Dm;
  const size_t we = (size_t)Dm * Dm;
  unsigned short* xb = (unsigned short*)carve(xe * 2);
  unsigned short* wqT = (unsigned short*)carve(we * 2);
  unsigned short* wkT = (unsigned short*)carve(we * 2);
  unsigned short* wvT = (unsigned short*)carve(we * 2);
  unsigned short* woT = (unsigned short*)carve(we * 2);
  unsigned short* qb = (unsigned short*)carve(xe * 2);
  unsigned short* kb = (unsigned short*)carve(xe * 2);
  unsigned short* vt = (unsigned short*)carve(xe * 2);
  unsigned short* ao = (unsigned short*)carve(xe * 2);
  (void)ws_size;

  cast_x_kernel<<<xe / 4 / 256, 256, 0, stream>>>(x, xb);
  transpose_w_kernel<<<dim3(16, 16, 4), 256, 0, stream>>>(Wq, Wk, Wv, Wo,
                                                          wqT, wkT, wvT, woT);
  gemm_qkv_kernel<<<384, 512, 0, stream>>>(xb, wqT, wkT, wvT, qb, kb, vt);
  attn_kernel<<<dim3(Bz * NH, 32), 256, 0, stream>>>(qb, kb, vt, ao);
  gemm_out_kernel<<<128, 512, 0, stream>>>(ao, woT, out);
}

// Round 8
// 249.619 us; speedup vs baseline: 1.0527x; 1.0527x over previous
//
#include <hip/hip_runtime.h>

// SelfAttention: B=4 S=2048 D=1024 H=16 HD=64, causal, fp32 in/out, bf16 MFMA compute.
// R16->R17: GEMM tile 256x256 -> 128x256 (same 8-wave phase-pipeline) for grid balance.
// R16: template worked (attn now top at 76.8us; both gemms <76.6) but grids were
// unbalanced: qkv 384 blocks @1/CU = 1.5 rounds -> makespan 2 rounds (75% eff);
// out 128 blocks -> HALF THE CHIP IDLE. 128x256 tiles: qkv 768 blocks = 3 exact
// rounds, out 256 = 1 exact round. Per-iter ring (glds units: A=2, B=4):
// prologue {t0:6, t1.A:2} vmcnt(2); steady: ph1{LDA8+LDBj01 || stg t'.B x4} ph2{LDBj23
// || stg t''.A x2, vmcnt(2)} ph3{buf1 || stg t''.B x4} ph4{|| stg t'''.A x2, vmcnt(2)};
// B stages deferred past jh=1 reads (units span both j-halves); peel vmcnt(0) at ph2.
// 96KB LDS, 1 block/CU. attn/cast/transpose byte-identical to R16 (control).

typedef __attribute__((ext_vector_type(8))) short short8_t;
typedef __attribute__((ext_vector_type(4))) short short4_t;
typedef __attribute__((ext_vector_type(4))) float float4_t;

constexpr int Bz = 4, Sq = 2048, Dm = 1024, NH = 16, HD = 64;

#define GLOAD_LDS16(g, l)                                                      \
  __builtin_amdgcn_global_load_lds(                                            \
      (const __attribute__((address_space(1))) unsigned int*)(g),              \
      (__attribute__((address_space(3))) unsigned int*)(l), 16, 0, 0)

__device__ __forceinline__ unsigned short f2bf(float f) {
  unsigned u = __builtin_bit_cast(unsigned, f);
  u += 0x7fffu + ((u >> 16) & 1u);
  return (unsigned short)(u >> 16);
}

__device__ __forceinline__ float exp2_fast(float x) {
#if __has_builtin(__builtin_amdgcn_exp2f)
  return __builtin_amdgcn_exp2f(x);
#else
  return exp2f(x);
#endif
}

__device__ __forceinline__ float m3(float a, float b, float c) {
  return fmaxf(fmaxf(a, b), c);  // clang emits v_max3_f32
}

__global__ __launch_bounds__(256) void cast_x_kernel(const float* __restrict__ x,
                                                     unsigned short* __restrict__ xb) {
  size_t i = (size_t)blockIdx.x * 256 + threadIdx.x;
  float4 v = ((const float4*)x)[i];
  ushort4 o;
  o.x = f2bf(v.x); o.y = f2bf(v.y); o.z = f2bf(v.z); o.w = f2bf(v.w);
  ((ushort4*)xb)[i] = o;
}

// All four W [K=1024][N=1024] fp32 -> WT [N][K] bf16 in one launch. grid (16,16,4).
__global__ __launch_bounds__(256) void transpose_w_kernel(
    const float* __restrict__ Wq, const float* __restrict__ Wk,
    const float* __restrict__ Wv, const float* __restrict__ Wo,
    unsigned short* __restrict__ wqT, unsigned short* __restrict__ wkT,
    unsigned short* __restrict__ wvT, unsigned short* __restrict__ woT) {
  __shared__ float tile[64][65];
  int zz = blockIdx.z;
  const float* W = zz == 0 ? Wq : (zz == 1 ? Wk : (zz == 2 ? Wv : Wo));
  unsigned short* WT = zz == 0 ? wqT : (zz == 1 ? wkT : (zz == 2 ? wvT : woT));
  int n0 = blockIdx.x * 64, k0 = blockIdx.y * 64;
  int tx = threadIdx.x & 63, ty = threadIdx.x >> 6;
#pragma unroll
  for (int i = 0; i < 16; ++i) {
    int r = i * 4 + ty;
    tile[r][tx] = W[(size_t)(k0 + r) * Dm + n0 + tx];
  }
  __syncthreads();
#pragma unroll
  for (int i = 0; i < 16; ++i) {
    int r = i * 4 + ty;
    WT[(size_t)(n0 + r) * Dm + k0 + tx] = f2bf(tile[tx][r]);
  }
}

// ---------------- 128x256 8-wave phase-pipelined mainloop ----------------
// smA: 2buf x [128][64] shorts (16KB/buf); smB: 2buf x [256][64] (32KB/buf) = 96KB.
// 8 waves = 2m x 4n; per-wave 64x64 output (acc[4][4]). 16B-granule XOR swizzle:
// LDS granule (row,g) holds source granule g^(row&7); reads XOR the same.
#define SBAR do { __builtin_amdgcn_sched_barrier(0); __builtin_amdgcn_s_barrier(); } while (0)
#define VMW(n_) asm volatile("s_waitcnt vmcnt(" #n_ ")" ::: "memory")

#define STGA2(buf_, kt_) do {                                                  \
  GLOAD_LDS16(gA + (size_t)lrow * Dm + (kt_) * 64 + csA,                       \
              smA + (buf_) * 8192 + tid * 8);                                  \
  GLOAD_LDS16(gA + (size_t)(lrow + 64) * Dm + (kt_) * 64 + csA,                \
              smA + (buf_) * 8192 + 4096 + tid * 8);                           \
} while (0)
#define STGB4(buf_, kt_) do {                                                  \
  GLOAD_LDS16(gB + (size_t)lrow * Dm + (kt_) * 64 + csA,                       \
              smB + (buf_) * 16384 + tid * 8);                                 \
  GLOAD_LDS16(gB + (size_t)(lrow + 64) * Dm + (kt_) * 64 + csA,                \
              smB + (buf_) * 16384 + 4096 + tid * 8);                          \
  GLOAD_LDS16(gB + (size_t)(lrow + 128) * Dm + (kt_) * 64 + csA,               \
              smB + (buf_) * 16384 + 8192 + tid * 8);                          \
  GLOAD_LDS16(gB + (size_t)(lrow + 192) * Dm + (kt_) * 64 + csA,               \
              smB + (buf_) * 16384 + 12288 + tid * 8);                         \
} while (0)
#define LDA8(buf_) do {                                                        \
  _Pragma("unroll") for (int i_ = 0; i_ < 4; ++i_) {                           \
    const unsigned short* p_ = smA + (buf_) * 8192 + aoff + i_ * 1024;         \
    a[i_][0] = *(const short8_t*)(p_ + csw0);                                  \
    a[i_][1] = *(const short8_t*)(p_ + csw1);                                  \
  }                                                                            \
} while (0)
#define LDB4(dst_, buf_, jh_) do {                                             \
  _Pragma("unroll") for (int j_ = 0; j_ < 2; ++j_) {                           \
    const unsigned short* p_ =                                                 \
        smB + (buf_) * 16384 + boff + ((jh_) * 2 + j_) * 1024;                 \
    dst_[j_][0] = *(const short8_t*)(p_ + csw0);                               \
    dst_[j_][1] = *(const short8_t*)(p_ + csw1);                               \
  }                                                                            \
} while (0)
#define MF16(breg_, joff_) do {                                                \
  __builtin_amdgcn_s_setprio(1);                                               \
  _Pragma("unroll") for (int i_ = 0; i_ < 4; ++i_)                             \
  _Pragma("unroll") for (int j_ = 0; j_ < 2; ++j_) {                           \
    acc[i_][(joff_) + j_] = __builtin_amdgcn_mfma_f32_16x16x32_bf16(           \
        a[i_][0], breg_[j_][0], acc[i_][(joff_) + j_], 0, 0, 0);               \
    acc[i_][(joff_) + j_] = __builtin_amdgcn_mfma_f32_16x16x32_bf16(           \
        a[i_][1], breg_[j_][1], acc[i_][(joff_) + j_], 0, 0, 0);               \
  }                                                                            \
  __builtin_amdgcn_s_setprio(0);                                               \
} while (0)

__device__ __forceinline__ void gemm128x256_mainloop(
    const unsigned short* __restrict__ A, const unsigned short* __restrict__ BT,
    int m0, int n0, unsigned short* smA, unsigned short* smB, float4_t acc[4][4]) {
  const int tid = threadIdx.x;
  const int lane = tid & 63, lr = lane & 15, quad = lane >> 4;
  const int wid = tid >> 6, wm = wid >> 2, wn = wid & 3;
  const int aoff = (wm * 64 + lr) * 64;     // A row base (shorts)
  const int boff = (wn * 64 + lr) * 64;     // B row base (shorts)
  const int csw0 = (quad ^ (lr & 7)) * 8;   // swizzled granule, kk=0
  const int csw1 = csw0 ^ 32;               // kk=1
  const int lrow = tid >> 3;                // staging row within a 64-row unit
  const int csA = ((tid & 7) ^ (lrow & 7)) * 8;  // pre-swizzled source col
  const unsigned short* gA = A + (size_t)m0 * Dm;
  const unsigned short* gB = BT + (size_t)n0 * Dm;

  short8_t a[4][2], bA[2][2], bB[2][2];

  // prologue: t0 full (6 glds) + t1.A (2); vmcnt(2) -> t0 landed, t1.A in flight
  STGA2(0, 0); STGB4(0, 0); STGA2(1, 1);
  VMW(2); SBAR;

#pragma unroll 1
  for (int T = 0; T < 7; ++T) {
    const int t1 = 2 * T + 1, t2 = 2 * T + 2, t3 = 2 * T + 3;
    // ph1: compute t(2T) j01 from buf0; stage t'(odd).B into buf1.B
    LDA8(0); LDB4(bA, 0, 0); STGB4(1, t1); SBAR; MF16(bA, 0); SBAR;
    // ph2: j23; stage t''.A; vmcnt(2) -> t' complete before ph3 reads buf1
    LDB4(bB, 0, 1); STGA2(0, t2); SBAR; MF16(bB, 2); VMW(2); SBAR;
    // ph3: compute t' j01 from buf1; stage t''.B into buf0.B
    LDA8(1); LDB4(bA, 1, 0); STGB4(0, t2); SBAR; MF16(bA, 0); SBAR;
    // ph4: j23; stage t'''.A; vmcnt(2) -> t'' complete before next ph1 reads buf0
    LDB4(bB, 1, 1); STGA2(1, t3); SBAR; MF16(bB, 2); VMW(2); SBAR;
  }
  // peel: t14 (buf0), t15 (buf1); ph1 stages t15.B; ph2 drains vmcnt(0)
  LDA8(0); LDB4(bA, 0, 0); STGB4(1, 15); SBAR; MF16(bA, 0); SBAR;
  LDB4(bB, 0, 1); SBAR; MF16(bB, 2); VMW(0); SBAR;
  LDA8(1); LDB4(bA, 1, 0); SBAR; MF16(bA, 0); SBAR;
  LDB4(bB, 1, 1); SBAR; MF16(bB, 2);
}

// QKV projections, 128x256 tiles. grid 768 linear (3 exact rounds), XCD cpx=96.
// Q,K -> [B,H,S,HD]; V -> TRANSPOSED [B,H,HD,S]. Q pre-scaled by 0.125*log2e.
__global__ __launch_bounds__(512, 2) void gemm_qkv_kernel(
    const unsigned short* __restrict__ xb,
    const unsigned short* __restrict__ wqT, const unsigned short* __restrict__ wkT,
    const unsigned short* __restrict__ wvT,
    unsigned short* __restrict__ qb, unsigned short* __restrict__ kb,
    unsigned short* __restrict__ vt) {
  __shared__ unsigned short smA[2 * 8192];
  __shared__ unsigned short smB[2 * 16384];
  int lin = (int)blockIdx.x;
  int logical = (lin & 7) * 96 + (lin >> 3);
  int bx = logical & 3;
  int by = (logical >> 2) & 63;
  int bz = logical >> 8;
  const unsigned short* WT = bz == 0 ? wqT : (bz == 1 ? wkT : wvT);
  unsigned short* outb = bz == 0 ? qb : (bz == 1 ? kb : vt);
  bool isV = bz == 2;
  float qscale = (bz == 0) ? 0.18033688011112042f : 1.0f;
  int m0 = by * 128, n0 = bx * 256;
  float4_t z = {0.f, 0.f, 0.f, 0.f};
  float4_t acc[4][4];
#pragma unroll
  for (int i = 0; i < 4; ++i)
#pragma unroll
    for (int j = 0; j < 4; ++j) acc[i][j] = z;
  gemm128x256_mainloop(xb, WT, m0, n0, smA, smB, acc);

  const int lane = threadIdx.x & 63, lr = lane & 15, quad = lane >> 4;
  const int wid = threadIdx.x >> 6, wm = wid >> 2, wn = wid & 3;
  const int mb = m0 + wm * 64 + quad * 4;
  const int nb = n0 + wn * 64 + lr;
  if (isV) {
#pragma unroll
    for (int ai = 0; ai < 4; ++ai)
#pragma unroll
      for (int bj = 0; bj < 4; ++bj) {
        int m = mb + ai * 16;
        int n = nb + bj * 16;
        int b = m >> 11, s = m & (Sq - 1);
        int h = n >> 6, hd = n & (HD - 1);
        ushort4 pk;
        pk.x = f2bf(acc[ai][bj][0]); pk.y = f2bf(acc[ai][bj][1]);
        pk.z = f2bf(acc[ai][bj][2]); pk.w = f2bf(acc[ai][bj][3]);
        *(ushort4*)(outb + (((size_t)b * NH + h) * HD + hd) * Sq + s) = pk;
      }
  } else {
#pragma unroll
    for (int ai = 0; ai < 4; ++ai)
#pragma unroll
      for (int bj = 0; bj < 4; ++bj)
#pragma unroll
        for (int r = 0; r < 4; ++r) {
          int m = mb + ai * 16 + r;
          int n = nb + bj * 16;
          int b = m >> 11, s = m & (Sq - 1);
          int h = n >> 6, hd = n & (HD - 1);
          outb[(((size_t)b * NH + h) * Sq + s) * HD + hd] = f2bf(acc[ai][bj][r] * qscale);
        }
  }
}

// Output projection: ao_bf16 [8192,1024] @ Wo -> fp32. grid 256 (1 exact round), cpx=32.
__global__ __launch_bounds__(512, 2) void gemm_out_kernel(
    const unsigned short* __restrict__ ao, const unsigned short* __restrict__ woT,
    float* __restrict__ out) {
  __shared__ unsigned short smA[2 * 8192];
  __shared__ unsigned short smB[2 * 16384];
  int lin = (int)blockIdx.x;
  int logical = (lin & 7) * 32 + (lin >> 3);
  int bx = logical & 3;
  int by = logical >> 2;
  int m0 = by * 128, n0 = bx * 256;
  float4_t z = {0.f, 0.f, 0.f, 0.f};
  float4_t acc[4][4];
#pragma unroll
  for (int i = 0; i < 4; ++i)
#pragma unroll
    for (int j = 0; j < 4; ++j) acc[i][j] = z;
  gemm128x256_mainloop(ao, woT, m0, n0, smA, smB, acc);

  const int lane = threadIdx.x & 63, lr = lane & 15, quad = lane >> 4;
  const int wid = threadIdx.x >> 6, wm = wid >> 2, wn = wid & 3;
  const int mb = m0 + wm * 64 + quad * 4;
  const int nb = n0 + wn * 64 + lr;
#pragma unroll
  for (int ai = 0; ai < 4; ++ai)
#pragma unroll
    for (int bj = 0; bj < 4; ++bj)
#pragma unroll
      for (int r = 0; r < 4; ++r) {
        int m = mb + ai * 16 + r;
        int n = nb + bj * 16;
        out[(size_t)m * Dm + n] = acc[ai][bj][r];
      }
}

// Flash attention — grid (B*H, 32), one 64-row q-tile per block, ti = 31 - blockIdx.y.
// Double-buffered K (glds, 16B-granule XOR) and V (reg-staged, 8B-slot XOR ^row&15).
__global__ __launch_bounds__(256) void attn_kernel(
    const unsigned short* __restrict__ qbuf, const unsigned short* __restrict__ kbuf,
    const unsigned short* __restrict__ vtbuf, unsigned short* __restrict__ ao) {
  __shared__ unsigned short lk[2 * 64 * 64];
  __shared__ unsigned short lv[2 * 64 * 64];
  int tid = threadIdx.x;
  int bh = blockIdx.x;
  int ti = 31 - (int)blockIdx.y;
  int wave = tid >> 6, lane = tid & 63;
  int lcol = lane & 15, quad = lane >> 4;
  int lc7 = lcol & 7;
  const unsigned short* Q = qbuf + (size_t)bh * Sq * HD;
  const unsigned short* K = kbuf + (size_t)bh * Sq * HD;
  const unsigned short* Vt = vtbuf + (size_t)bh * HD * Sq;
  int b = bh >> 4, h = bh & 15;
  float4_t z = {0.f, 0.f, 0.f, 0.f};

  // --- K staging map (glds direct, 16B granule g ^= row&7) ---
  const int r0 = tid >> 3;                    // 0..31 (second call: +32)
  const int sgk = (tid & 7) ^ (r0 & 7);       // pre-swizzled source granule
  const unsigned short* kg = K + (size_t)r0 * HD + sgk * 8;  // += 64*HD per tile
  const int kdst = tid * 8;                   // linear dest (shorts)

  // --- V staging map (reg-staged, 8B slot d = w ^ (row&15)) ---
  const int w0 = (tid & 7) * 2;
  const int xa = r0 & 15;
  const int d0 = w0 ^ xa;                     // LDS slot holding content slot w0
  const unsigned short* vsrc = Vt + (size_t)r0 * Sq + w0 * 4;  // += 64 per tile
  const int vdst = r0 * 64 + d0 * 4;          // shorts; partner slot = vdst ^ 4

  // --- swizzled read offsets ---
  const int koff0 = (quad ^ lc7) * 8;
  const int koff1 = ((quad | 4) ^ lc7) * 8;
  int voff[4];
#pragma unroll
  for (int s4 = 0; s4 < 4; ++s4) voff[s4] = ((s4 * 4 + quad) ^ lcol) * 4;

  unsigned short* lkc = lk;
  unsigned short* lkn = lk + 4096;
  unsigned short* lvc = lv;
  unsigned short* lvn = lv + 4096;

  int q0w = ti * 64 + wave * 16;
  int q_global = q0w + lcol;
  short8_t qf0 = *(const short8_t*)(Q + (size_t)(q0w + lcol) * HD + quad * 8);
  short8_t qf1 = *(const short8_t*)(Q + (size_t)(q0w + lcol) * HD + 32 + quad * 8);
  float m_i = -INFINITY, l_i = 0.f;
  float4_t o[4];
#pragma unroll
  for (int f = 0; f < 4; ++f) o[f] = z;

  // --- prologue: stage tile 0 into current buffers ---
  {
    GLOAD_LDS16(kg, lkc + kdst);
    GLOAD_LDS16(kg + (size_t)32 * HD, lkc + 2048 + kdst);
    short4_t a0 = *(const short4_t*)(vsrc);
    short4_t a1 = *(const short4_t*)(vsrc + 4);
    short4_t b0 = *(const short4_t*)(vsrc + (size_t)32 * Sq);
    short4_t b1 = *(const short4_t*)(vsrc + (size_t)32 * Sq + 4);
    *(short4_t*)(lvc + vdst) = a0;
    *(short4_t*)(lvc + (vdst ^ 4)) = a1;
    *(short4_t*)(lvc + vdst + 2048) = b0;
    *(short4_t*)(lvc + (vdst ^ 4) + 2048) = b1;
  }
  __syncthreads();

  int nkt = ti + 1;
  for (int kt = 0; kt < nkt; ++kt) {
    bool has_next = (kt + 1 < nkt);
    short4_t a0, a1, b0, b1;
    if (has_next) {
      const unsigned short* vs = vsrc + (size_t)(kt + 1) * 64;
      a0 = *(const short4_t*)(vs);
      a1 = *(const short4_t*)(vs + 4);
      b0 = *(const short4_t*)(vs + (size_t)32 * Sq);
      b1 = *(const short4_t*)(vs + (size_t)32 * Sq + 4);
      const unsigned short* kgn = kg + (size_t)(kt + 1) * 64 * HD;
      GLOAD_LDS16(kgn, lkn + kdst);
      GLOAD_LDS16(kgn + (size_t)32 * HD, lkn + 2048 + kdst);
    }

    // --- QK^T from lkc ---
    float s[16];
#pragma unroll
    for (int s4 = 0; s4 < 4; ++s4) {
      const unsigned short* kr = lkc + (s4 * 16 + lcol) * 64;
      short8_t kf0 = *(const short8_t*)(kr + koff0);
      short8_t kf1 = *(const short8_t*)(kr + koff1);
      float4_t st = z;
      st = __builtin_amdgcn_mfma_f32_16x16x32_bf16(kf0, qf0, st, 0, 0, 0);
      st = __builtin_amdgcn_mfma_f32_16x16x32_bf16(kf1, qf1, st, 0, 0, 0);
#pragma unroll
      for (int r = 0; r < 4; ++r) s[s4 * 4 + r] = st[r];
    }
    if (kt == ti) {  // diagonal tile: causal mask (uniform branch)
      int key0 = kt * 64;
#pragma unroll
      for (int s4 = 0; s4 < 4; ++s4)
#pragma unroll
        for (int r = 0; r < 4; ++r)
          if (key0 + s4 * 16 + quad * 4 + r > q_global) s[s4 * 4 + r] = -INFINITY;
    }

    // max3-tree reduction over 16 values
    float ta = m3(s[0], s[1], s[2]);
    float tb = m3(s[3], s[4], s[5]);
    float tc = m3(s[6], s[7], s[8]);
    float td = m3(s[9], s[10], s[11]);
    float te = m3(s[12], s[13], s[14]);
    float tmax = m3(ta, tb, tc);
    tmax = m3(tmax, td, te);
    tmax = fmaxf(tmax, s[15]);
    tmax = fmaxf(tmax, __shfl_xor(tmax, 16, 64));
    tmax = fmaxf(tmax, __shfl_xor(tmax, 32, 64));

    // T13 defer-max (log2 domain, THR=8 -> P bounded by 256)
    if (__any(tmax > m_i + 8.f)) {
      float m_new = fmaxf(m_i, tmax);
      float alpha = exp2_fast(m_i - m_new);
      l_i *= alpha;
      m_i = m_new;
      float at[4];
#pragma unroll
      for (int r = 0; r < 4; ++r) at[r] = __shfl(alpha, quad * 4 + r, 64);
#pragma unroll
      for (int f = 0; f < 4; ++f)
#pragma unroll
        for (int r = 0; r < 4; ++r) o[f][r] *= at[r];
    }

    float psum = 0.f;
    short4_t pf[4];
#pragma unroll
    for (int s4 = 0; s4 < 4; ++s4) {
      float p0 = exp2_fast(s[s4 * 4 + 0] - m_i);
      float p1 = exp2_fast(s[s4 * 4 + 1] - m_i);
      float p2 = exp2_fast(s[s4 * 4 + 2] - m_i);
      float p3 = exp2_fast(s[s4 * 4 + 3] - m_i);
      psum += (p0 + p1) + (p2 + p3);
      unsigned lo, hi;
      asm("v_cvt_pk_bf16_f32 %0, %1, %2" : "=v"(lo) : "v"(p0), "v"(p1));
      asm("v_cvt_pk_bf16_f32 %0, %1, %2" : "=v"(hi) : "v"(p2), "v"(p3));
      uint2 packed;
      packed.x = lo;
      packed.y = hi;
      pf[s4] = __builtin_bit_cast(short4_t, packed);
    }
    psum += __shfl_xor(psum, 16, 64);
    psum += __shfl_xor(psum, 32, 64);
    l_i += psum;

    // --- write next-tile V into alternate buffer (vmcnt wait was hidden above) ---
    if (has_next) {
      *(short4_t*)(lvn + vdst) = a0;
      *(short4_t*)(lvn + (vdst ^ 4)) = a1;
      *(short4_t*)(lvn + vdst + 2048) = b0;
      *(short4_t*)(lvn + (vdst ^ 4) + 2048) = b1;
    }

    // --- PV from lvc (conflict-free swizzled b64 reads) ---
#pragma unroll
    for (int f = 0; f < 4; ++f) {
      const unsigned short* vr = lvc + (f * 16 + lcol) * 64;
#pragma unroll
      for (int s4 = 0; s4 < 4; ++s4) {
        short4_t vf = *(const short4_t*)(vr + voff[s4]);
        o[f] = __builtin_amdgcn_mfma_f32_16x16x16bf16_1k(pf[s4], vf, o[f], 0, 0, 0);
      }
    }

    __syncthreads();  // drains K glds (vmcnt0) + V ds_writes; buffers swap
    unsigned short* t;
    t = lkc; lkc = lkn; lkn = t;
    t = lvc; lvc = lvn; lvn = t;
  }

  float lt[4];
#pragma unroll
  for (int r = 0; r < 4; ++r) lt[r] = 1.f / __shfl(l_i, quad * 4 + r, 64);
#pragma unroll
  for (int f = 0; f < 4; ++f)
#pragma unroll
    for (int r = 0; r < 4; ++r) {
      int q = q0w + quad * 4 + r;
      int hd = f * 16 + lcol;
      ao[((size_t)b * Sq + q) * (NH * HD) + h * HD + hd] = f2bf(o[f][r] * lt[r]);
    }
}

extern "C" void kernel_launch(void* const* d_in, const int* in_sizes, int n_in,
                              void* d_out, int out_size, void* d_ws, size_t ws_size,
                              hipStream_t stream) {
  const float* x = (const float*)d_in[0];
  const float* Wq = (const float*)d_in[1];
  const float* Wk = (const float*)d_in[2];
  const float* Wv = (const float*)d_in[3];
  const float* Wo = (const float*)d_in[4];
  float* out = (float*)d_out;

  char* ws = (char*)d_ws;
  size_t off = 0;
  auto carve = [&](size_t bytes) {
    void* p = ws + off;
    off += (bytes + 255) & ~(size_t)255;
    return p;
  };
  const size_t xe = (size_t)Bz * Sq * Dm;
  const size_t we = (size_t)Dm * Dm;
  unsigned short* xb = (unsigned short*)carve(xe * 2);
  unsigned short* wqT = (unsigned short*)carve(we * 2);
  unsigned short* wkT = (unsigned short*)carve(we * 2);
  unsigned short* wvT = (unsigned short*)carve(we * 2);
  unsigned short* woT = (unsigned short*)carve(we * 2);
  unsigned short* qb = (unsigned short*)carve(xe * 2);
  unsigned short* kb = (unsigned short*)carve(xe * 2);
  unsigned short* vt = (unsigned short*)carve(xe * 2);
  unsigned short* ao = (unsigned short*)carve(xe * 2);
  (void)ws_size;

  cast_x_kernel<<<xe / 4 / 256, 256, 0, stream>>>(x, xb);
  transpose_w_kernel<<<dim3(16, 16, 4), 256, 0, stream>>>(Wq, Wk, Wv, Wo,
                                                          wqT, wkT, wvT, woT);
  gemm_qkv_kernel<<<768, 512, 0, stream>>>(xb, wqT, wkT, wvT, qb, kb, vt);
  attn_kernel<<<dim3(Bz * NH, 32), 256, 0, stream>>>(qb, kb, vt, ao);
  gemm_out_kernel<<<256, 512, 0, stream>>>(ao, woT, out);
}

// Round 9
// 246.709 us; speedup vs baseline: 1.0651x; 1.0118x over previous
//
#include <hip/hip_runtime.h>

// SelfAttention: B=4 S=2048 D=1024 H=16 HD=64, causal, fp32 in/out, bf16 MFMA compute.
// R17->R18: attn q-rows per wave 16 -> 32 (128-row q-block, same 4 waves/64-key tiles).
// R17 counters: attn 76.4us top kernel; MfmaUtil 29 + VALUBusy 63 (~92% issue-bound);
// LDS pipe ~68%: each wave reads FULL K (8 b128) + V (16 b64) tiles to serve only
// 16 q-rows. In mfma(K,Q), K/V fragments are shared -> a second Q/P operand pair
// costs ZERO extra LDS reads. 128-row blocks: tile-steps 33792->17408 (1.94x), LDS
// traffic/score and K/V HBM re-reads halve, barriers halve; MFMA/exp totals unchanged
// -> VALU becomes the clean bound (~48us floor). Fully-masked tiles skipped via
// wave-uniform `active` guard (barriers uniform). grid (64,16), ti=15-y big-first.
// GEMMs (128x256 8-wave phase pipeline), cast, transpose byte-identical to R17.

typedef __attribute__((ext_vector_type(8))) short short8_t;
typedef __attribute__((ext_vector_type(4))) short short4_t;
typedef __attribute__((ext_vector_type(4))) float float4_t;

constexpr int Bz = 4, Sq = 2048, Dm = 1024, NH = 16, HD = 64;

#define GLOAD_LDS16(g, l)                                                      \
  __builtin_amdgcn_global_load_lds(                                            \
      (const __attribute__((address_space(1))) unsigned int*)(g),              \
      (__attribute__((address_space(3))) unsigned int*)(l), 16, 0, 0)

__device__ __forceinline__ unsigned short f2bf(float f) {
  unsigned u = __builtin_bit_cast(unsigned, f);
  u += 0x7fffu + ((u >> 16) & 1u);
  return (unsigned short)(u >> 16);
}

__device__ __forceinline__ float exp2_fast(float x) {
#if __has_builtin(__builtin_amdgcn_exp2f)
  return __builtin_amdgcn_exp2f(x);
#else
  return exp2f(x);
#endif
}

__device__ __forceinline__ float m3(float a, float b, float c) {
  return fmaxf(fmaxf(a, b), c);  // clang emits v_max3_f32
}

__global__ __launch_bounds__(256) void cast_x_kernel(const float* __restrict__ x,
                                                     unsigned short* __restrict__ xb) {
  size_t i = (size_t)blockIdx.x * 256 + threadIdx.x;
  float4 v = ((const float4*)x)[i];
  ushort4 o;
  o.x = f2bf(v.x); o.y = f2bf(v.y); o.z = f2bf(v.z); o.w = f2bf(v.w);
  ((ushort4*)xb)[i] = o;
}

// All four W [K=1024][N=1024] fp32 -> WT [N][K] bf16 in one launch. grid (16,16,4).
__global__ __launch_bounds__(256) void transpose_w_kernel(
    const float* __restrict__ Wq, const float* __restrict__ Wk,
    const float* __restrict__ Wv, const float* __restrict__ Wo,
    unsigned short* __restrict__ wqT, unsigned short* __restrict__ wkT,
    unsigned short* __restrict__ wvT, unsigned short* __restrict__ woT) {
  __shared__ float tile[64][65];
  int zz = blockIdx.z;
  const float* W = zz == 0 ? Wq : (zz == 1 ? Wk : (zz == 2 ? Wv : Wo));
  unsigned short* WT = zz == 0 ? wqT : (zz == 1 ? wkT : (zz == 2 ? wvT : woT));
  int n0 = blockIdx.x * 64, k0 = blockIdx.y * 64;
  int tx = threadIdx.x & 63, ty = threadIdx.x >> 6;
#pragma unroll
  for (int i = 0; i < 16; ++i) {
    int r = i * 4 + ty;
    tile[r][tx] = W[(size_t)(k0 + r) * Dm + n0 + tx];
  }
  __syncthreads();
#pragma unroll
  for (int i = 0; i < 16; ++i) {
    int r = i * 4 + ty;
    WT[(size_t)(n0 + r) * Dm + k0 + tx] = f2bf(tile[tx][r]);
  }
}

// ---------------- 128x256 8-wave phase-pipelined mainloop ----------------
#define SBAR do { __builtin_amdgcn_sched_barrier(0); __builtin_amdgcn_s_barrier(); } while (0)
#define VMW(n_) asm volatile("s_waitcnt vmcnt(" #n_ ")" ::: "memory")

#define STGA2(buf_, kt_) do {                                                  \
  GLOAD_LDS16(gA + (size_t)lrow * Dm + (kt_) * 64 + csA,                       \
              smA + (buf_) * 8192 + tid * 8);                                  \
  GLOAD_LDS16(gA + (size_t)(lrow + 64) * Dm + (kt_) * 64 + csA,                \
              smA + (buf_) * 8192 + 4096 + tid * 8);                           \
} while (0)
#define STGB4(buf_, kt_) do {                                                  \
  GLOAD_LDS16(gB + (size_t)lrow * Dm + (kt_) * 64 + csA,                       \
              smB + (buf_) * 16384 + tid * 8);                                 \
  GLOAD_LDS16(gB + (size_t)(lrow + 64) * Dm + (kt_) * 64 + csA,                \
              smB + (buf_) * 16384 + 4096 + tid * 8);                          \
  GLOAD_LDS16(gB + (size_t)(lrow + 128) * Dm + (kt_) * 64 + csA,               \
              smB + (buf_) * 16384 + 8192 + tid * 8);                          \
  GLOAD_LDS16(gB + (size_t)(lrow + 192) * Dm + (kt_) * 64 + csA,               \
              smB + (buf_) * 16384 + 12288 + tid * 8);                         \
} while (0)
#define LDA8(buf_) do {                                                        \
  _Pragma("unroll") for (int i_ = 0; i_ < 4; ++i_) {                           \
    const unsigned short* p_ = smA + (buf_) * 8192 + aoff + i_ * 1024;         \
    a[i_][0] = *(const short8_t*)(p_ + csw0);                                  \
    a[i_][1] = *(const short8_t*)(p_ + csw1);                                  \
  }                                                                            \
} while (0)
#define LDB4(dst_, buf_, jh_) do {                                             \
  _Pragma("unroll") for (int j_ = 0; j_ < 2; ++j_) {                           \
    const unsigned short* p_ =                                                 \
        smB + (buf_) * 16384 + boff + ((jh_) * 2 + j_) * 1024;                 \
    dst_[j_][0] = *(const short8_t*)(p_ + csw0);                               \
    dst_[j_][1] = *(const short8_t*)(p_ + csw1);                               \
  }                                                                            \
} while (0)
#define MF16(breg_, joff_) do {                                                \
  __builtin_amdgcn_s_setprio(1);                                               \
  _Pragma("unroll") for (int i_ = 0; i_ < 4; ++i_)                             \
  _Pragma("unroll") for (int j_ = 0; j_ < 2; ++j_) {                           \
    acc[i_][(joff_) + j_] = __builtin_amdgcn_mfma_f32_16x16x32_bf16(           \
        a[i_][0], breg_[j_][0], acc[i_][(joff_) + j_], 0, 0, 0);               \
    acc[i_][(joff_) + j_] = __builtin_amdgcn_mfma_f32_16x16x32_bf16(           \
        a[i_][1], breg_[j_][1], acc[i_][(joff_) + j_], 0, 0, 0);               \
  }                                                                            \
  __builtin_amdgcn_s_setprio(0);                                               \
} while (0)

__device__ __forceinline__ void gemm128x256_mainloop(
    const unsigned short* __restrict__ A, const unsigned short* __restrict__ BT,
    int m0, int n0, unsigned short* smA, unsigned short* smB, float4_t acc[4][4]) {
  const int tid = threadIdx.x;
  const int lane = tid & 63, lr = lane & 15, quad = lane >> 4;
  const int wid = tid >> 6, wm = wid >> 2, wn = wid & 3;
  const int aoff = (wm * 64 + lr) * 64;
  const int boff = (wn * 64 + lr) * 64;
  const int csw0 = (quad ^ (lr & 7)) * 8;
  const int csw1 = csw0 ^ 32;
  const int lrow = tid >> 3;
  const int csA = ((tid & 7) ^ (lrow & 7)) * 8;
  const unsigned short* gA = A + (size_t)m0 * Dm;
  const unsigned short* gB = BT + (size_t)n0 * Dm;

  short8_t a[4][2], bA[2][2], bB[2][2];

  STGA2(0, 0); STGB4(0, 0); STGA2(1, 1);
  VMW(2); SBAR;

#pragma unroll 1
  for (int T = 0; T < 7; ++T) {
    const int t1 = 2 * T + 1, t2 = 2 * T + 2, t3 = 2 * T + 3;
    LDA8(0); LDB4(bA, 0, 0); STGB4(1, t1); SBAR; MF16(bA, 0); SBAR;
    LDB4(bB, 0, 1); STGA2(0, t2); SBAR; MF16(bB, 2); VMW(2); SBAR;
    LDA8(1); LDB4(bA, 1, 0); STGB4(0, t2); SBAR; MF16(bA, 0); SBAR;
    LDB4(bB, 1, 1); STGA2(1, t3); SBAR; MF16(bB, 2); VMW(2); SBAR;
  }
  LDA8(0); LDB4(bA, 0, 0); STGB4(1, 15); SBAR; MF16(bA, 0); SBAR;
  LDB4(bB, 0, 1); SBAR; MF16(bB, 2); VMW(0); SBAR;
  LDA8(1); LDB4(bA, 1, 0); SBAR; MF16(bA, 0); SBAR;
  LDB4(bB, 1, 1); SBAR; MF16(bB, 2);
}

// QKV projections, 128x256 tiles. grid 768 linear (3 exact rounds), XCD cpx=96.
__global__ __launch_bounds__(512, 2) void gemm_qkv_kernel(
    const unsigned short* __restrict__ xb,
    const unsigned short* __restrict__ wqT, const unsigned short* __restrict__ wkT,
    const unsigned short* __restrict__ wvT,
    unsigned short* __restrict__ qb, unsigned short* __restrict__ kb,
    unsigned short* __restrict__ vt) {
  __shared__ unsigned short smA[2 * 8192];
  __shared__ unsigned short smB[2 * 16384];
  int lin = (int)blockIdx.x;
  int logical = (lin & 7) * 96 + (lin >> 3);
  int bx = logical & 3;
  int by = (logical >> 2) & 63;
  int bz = logical >> 8;
  const unsigned short* WT = bz == 0 ? wqT : (bz == 1 ? wkT : wvT);
  unsigned short* outb = bz == 0 ? qb : (bz == 1 ? kb : vt);
  bool isV = bz == 2;
  float qscale = (bz == 0) ? 0.18033688011112042f : 1.0f;
  int m0 = by * 128, n0 = bx * 256;
  float4_t z = {0.f, 0.f, 0.f, 0.f};
  float4_t acc[4][4];
#pragma unroll
  for (int i = 0; i < 4; ++i)
#pragma unroll
    for (int j = 0; j < 4; ++j) acc[i][j] = z;
  gemm128x256_mainloop(xb, WT, m0, n0, smA, smB, acc);

  const int lane = threadIdx.x & 63, lr = lane & 15, quad = lane >> 4;
  const int wid = threadIdx.x >> 6, wm = wid >> 2, wn = wid & 3;
  const int mb = m0 + wm * 64 + quad * 4;
  const int nb = n0 + wn * 64 + lr;
  if (isV) {
#pragma unroll
    for (int ai = 0; ai < 4; ++ai)
#pragma unroll
      for (int bj = 0; bj < 4; ++bj) {
        int m = mb + ai * 16;
        int n = nb + bj * 16;
        int b = m >> 11, s = m & (Sq - 1);
        int h = n >> 6, hd = n & (HD - 1);
        ushort4 pk;
        pk.x = f2bf(acc[ai][bj][0]); pk.y = f2bf(acc[ai][bj][1]);
        pk.z = f2bf(acc[ai][bj][2]); pk.w = f2bf(acc[ai][bj][3]);
        *(ushort4*)(outb + (((size_t)b * NH + h) * HD + hd) * Sq + s) = pk;
      }
  } else {
#pragma unroll
    for (int ai = 0; ai < 4; ++ai)
#pragma unroll
      for (int bj = 0; bj < 4; ++bj)
#pragma unroll
        for (int r = 0; r < 4; ++r) {
          int m = mb + ai * 16 + r;
          int n = nb + bj * 16;
          int b = m >> 11, s = m & (Sq - 1);
          int h = n >> 6, hd = n & (HD - 1);
          outb[(((size_t)b * NH + h) * Sq + s) * HD + hd] = f2bf(acc[ai][bj][r] * qscale);
        }
  }
}

// Output projection: ao_bf16 [8192,1024] @ Wo -> fp32. grid 256 (1 exact round), cpx=32.
__global__ __launch_bounds__(512, 2) void gemm_out_kernel(
    const unsigned short* __restrict__ ao, const unsigned short* __restrict__ woT,
    float* __restrict__ out) {
  __shared__ unsigned short smA[2 * 8192];
  __shared__ unsigned short smB[2 * 16384];
  int lin = (int)blockIdx.x;
  int logical = (lin & 7) * 32 + (lin >> 3);
  int bx = logical & 3;
  int by = logical >> 2;
  int m0 = by * 128, n0 = bx * 256;
  float4_t z = {0.f, 0.f, 0.f, 0.f};
  float4_t acc[4][4];
#pragma unroll
  for (int i = 0; i < 4; ++i)
#pragma unroll
    for (int j = 0; j < 4; ++j) acc[i][j] = z;
  gemm128x256_mainloop(ao, woT, m0, n0, smA, smB, acc);

  const int lane = threadIdx.x & 63, lr = lane & 15, quad = lane >> 4;
  const int wid = threadIdx.x >> 6, wm = wid >> 2, wn = wid & 3;
  const int mb = m0 + wm * 64 + quad * 4;
  const int nb = n0 + wn * 64 + lr;
#pragma unroll
  for (int ai = 0; ai < 4; ++ai)
#pragma unroll
    for (int bj = 0; bj < 4; ++bj)
#pragma unroll
      for (int r = 0; r < 4; ++r) {
        int m = mb + ai * 16 + r;
        int n = nb + bj * 16;
        out[(size_t)m * Dm + n] = acc[ai][bj][r];
      }
}

// Flash attention — grid (B*H, 16), 128-row q-tile per block, 4 waves x 32 q-rows.
// ti = 15 - blockIdx.y (big tiles first). K/V fragments shared by both 16-row groups
// per wave -> 2x q-rows at zero extra LDS reads. Double-buffered K (glds, 16B XOR)
// and V (reg-staged, 8B-slot XOR ^row&15). Fully-masked tiles: wave-uniform skip.
__global__ __launch_bounds__(256) void attn_kernel(
    const unsigned short* __restrict__ qbuf, const unsigned short* __restrict__ kbuf,
    const unsigned short* __restrict__ vtbuf, unsigned short* __restrict__ ao) {
  __shared__ unsigned short lk[2 * 64 * 64];
  __shared__ unsigned short lv[2 * 64 * 64];
  int tid = threadIdx.x;
  int bh = blockIdx.x;
  int ti = 15 - (int)blockIdx.y;
  int wave = tid >> 6, lane = tid & 63;
  int lcol = lane & 15, quad = lane >> 4;
  int lc7 = lcol & 7;
  const unsigned short* Q = qbuf + (size_t)bh * Sq * HD;
  const unsigned short* K = kbuf + (size_t)bh * Sq * HD;
  const unsigned short* Vt = vtbuf + (size_t)bh * HD * Sq;
  int b = bh >> 4, h = bh & 15;
  float4_t z = {0.f, 0.f, 0.f, 0.f};

  // --- K staging map (glds direct, 16B granule g ^= row&7) ---
  const int r0 = tid >> 3;
  const int sgk = (tid & 7) ^ (r0 & 7);
  const unsigned short* kg = K + (size_t)r0 * HD + sgk * 8;
  const int kdst = tid * 8;

  // --- V staging map (reg-staged, 8B slot d = w ^ (row&15)) ---
  const int w0 = (tid & 7) * 2;
  const int xa = r0 & 15;
  const int d0 = w0 ^ xa;
  const unsigned short* vsrc = Vt + (size_t)r0 * Sq + w0 * 4;
  const int vdst = r0 * 64 + d0 * 4;

  // --- swizzled read offsets ---
  const int koff0 = (quad ^ lc7) * 8;
  const int koff1 = ((quad | 4) ^ lc7) * 8;
  int voff[4];
#pragma unroll
  for (int s4 = 0; s4 < 4; ++s4) voff[s4] = ((s4 * 4 + quad) ^ lcol) * 4;

  unsigned short* lkc = lk;
  unsigned short* lkn = lk + 4096;
  unsigned short* lvc = lv;
  unsigned short* lvn = lv + 4096;

  int q0w = ti * 128 + wave * 32;       // wave owns rows [q0w, q0w+31]
  int qg0 = q0w + lcol;                 // group0 row
  int qg1 = q0w + 16 + lcol;            // group1 row
  const unsigned short* Qb0 = Q + (size_t)qg0 * HD;
  const unsigned short* Qb1 = Q + (size_t)qg1 * HD;
  short8_t qf0 = *(const short8_t*)(Qb0 + quad * 8);
  short8_t qf1 = *(const short8_t*)(Qb0 + 32 + quad * 8);
  short8_t qf2 = *(const short8_t*)(Qb1 + quad * 8);
  short8_t qf3 = *(const short8_t*)(Qb1 + 32 + quad * 8);
  float mi0 = -INFINITY, li0 = 0.f;
  float mi1 = -INFINITY, li1 = 0.f;
  float4_t o0[4], o1[4];
#pragma unroll
  for (int f = 0; f < 4; ++f) { o0[f] = z; o1[f] = z; }

  // --- prologue: stage tile 0 ---
  {
    GLOAD_LDS16(kg, lkc + kdst);
    GLOAD_LDS16(kg + (size_t)32 * HD, lkc + 2048 + kdst);
    short4_t a0 = *(const short4_t*)(vsrc);
    short4_t a1 = *(const short4_t*)(vsrc + 4);
    short4_t b0 = *(const short4_t*)(vsrc + (size_t)32 * Sq);
    short4_t b1 = *(const short4_t*)(vsrc + (size_t)32 * Sq + 4);
    *(short4_t*)(lvc + vdst) = a0;
    *(short4_t*)(lvc + (vdst ^ 4)) = a1;
    *(short4_t*)(lvc + vdst + 2048) = b0;
    *(short4_t*)(lvc + (vdst ^ 4) + 2048) = b1;
  }
  __syncthreads();

  int nkt = 2 * ti + 2;
  for (int kt = 0; kt < nkt; ++kt) {
    int key0 = kt * 64;
    bool has_next = (kt + 1 < nkt);
    short4_t va0, va1, vb0, vb1;
    if (has_next) {
      const unsigned short* vs = vsrc + (size_t)(kt + 1) * 64;
      va0 = *(const short4_t*)(vs);
      va1 = *(const short4_t*)(vs + 4);
      vb0 = *(const short4_t*)(vs + (size_t)32 * Sq);
      vb1 = *(const short4_t*)(vs + (size_t)32 * Sq + 4);
      const unsigned short* kgn = kg + (size_t)(kt + 1) * 64 * HD;
      GLOAD_LDS16(kgn, lkn + kdst);
      GLOAD_LDS16(kgn + (size_t)32 * HD, lkn + 2048 + kdst);
    }

    bool active = (key0 <= q0w + 31);   // wave-uniform
    short4_t pf0[4], pf1[4];
    if (active) {
      // --- QK^T: shared kf fragments feed BOTH q-groups ---
      float s0[16], s1[16];
#pragma unroll
      for (int s4 = 0; s4 < 4; ++s4) {
        const unsigned short* kr = lkc + (s4 * 16 + lcol) * 64;
        short8_t kf0 = *(const short8_t*)(kr + koff0);
        short8_t kf1 = *(const short8_t*)(kr + koff1);
        float4_t st0 = z, st1 = z;
        st0 = __builtin_amdgcn_mfma_f32_16x16x32_bf16(kf0, qf0, st0, 0, 0, 0);
        st0 = __builtin_amdgcn_mfma_f32_16x16x32_bf16(kf1, qf1, st0, 0, 0, 0);
        st1 = __builtin_amdgcn_mfma_f32_16x16x32_bf16(kf0, qf2, st1, 0, 0, 0);
        st1 = __builtin_amdgcn_mfma_f32_16x16x32_bf16(kf1, qf3, st1, 0, 0, 0);
#pragma unroll
        for (int r = 0; r < 4; ++r) { s0[s4 * 4 + r] = st0[r]; s1[s4 * 4 + r] = st1[r]; }
      }
      if (key0 + 63 > q0w) {  // diagonal region: mask (per-group exact rows)
#pragma unroll
        for (int s4 = 0; s4 < 4; ++s4)
#pragma unroll
          for (int r = 0; r < 4; ++r) {
            int key = key0 + s4 * 16 + quad * 4 + r;
            if (key > qg0) s0[s4 * 4 + r] = -INFINITY;
            if (key > qg1) s1[s4 * 4 + r] = -INFINITY;
          }
      }

      // --- group 0 softmax ---
      {
        float ta = m3(s0[0], s0[1], s0[2]);
        float tb = m3(s0[3], s0[4], s0[5]);
        float tc = m3(s0[6], s0[7], s0[8]);
        float td = m3(s0[9], s0[10], s0[11]);
        float te = m3(s0[12], s0[13], s0[14]);
        float tmax = m3(ta, tb, tc);
        tmax = m3(tmax, td, te);
        tmax = fmaxf(tmax, s0[15]);
        tmax = fmaxf(tmax, __shfl_xor(tmax, 16, 64));
        tmax = fmaxf(tmax, __shfl_xor(tmax, 32, 64));
        if (__any(tmax > mi0 + 8.f)) {
          float m_new = fmaxf(mi0, tmax);
          float alpha = exp2_fast(mi0 - m_new);
          li0 *= alpha;
          mi0 = m_new;
          float at[4];
#pragma unroll
          for (int r = 0; r < 4; ++r) at[r] = __shfl(alpha, quad * 4 + r, 64);
#pragma unroll
          for (int f = 0; f < 4; ++f)
#pragma unroll
            for (int r = 0; r < 4; ++r) o0[f][r] *= at[r];
        }
        float psum = 0.f;
#pragma unroll
        for (int s4 = 0; s4 < 4; ++s4) {
          float p0 = exp2_fast(s0[s4 * 4 + 0] - mi0);
          float p1 = exp2_fast(s0[s4 * 4 + 1] - mi0);
          float p2 = exp2_fast(s0[s4 * 4 + 2] - mi0);
          float p3 = exp2_fast(s0[s4 * 4 + 3] - mi0);
          psum += (p0 + p1) + (p2 + p3);
          unsigned lo, hi;
          asm("v_cvt_pk_bf16_f32 %0, %1, %2" : "=v"(lo) : "v"(p0), "v"(p1));
          asm("v_cvt_pk_bf16_f32 %0, %1, %2" : "=v"(hi) : "v"(p2), "v"(p3));
          uint2 packed; packed.x = lo; packed.y = hi;
          pf0[s4] = __builtin_bit_cast(short4_t, packed);
        }
        psum += __shfl_xor(psum, 16, 64);
        psum += __shfl_xor(psum, 32, 64);
        li0 += psum;
      }
      // --- group 1 softmax ---
      {
        float ta = m3(s1[0], s1[1], s1[2]);
        float tb = m3(s1[3], s1[4], s1[5]);
        float tc = m3(s1[6], s1[7], s1[8]);
        float td = m3(s1[9], s1[10], s1[11]);
        float te = m3(s1[12], s1[13], s1[14]);
        float tmax = m3(ta, tb, tc);
        tmax = m3(tmax, td, te);
        tmax = fmaxf(tmax, s1[15]);
        tmax = fmaxf(tmax, __shfl_xor(tmax, 16, 64));
        tmax = fmaxf(tmax, __shfl_xor(tmax, 32, 64));
        if (__any(tmax > mi1 + 8.f)) {
          float m_new = fmaxf(mi1, tmax);
          float alpha = exp2_fast(mi1 - m_new);
          li1 *= alpha;
          mi1 = m_new;
          float at[4];
#pragma unroll
          for (int r = 0; r < 4; ++r) at[r] = __shfl(alpha, quad * 4 + r, 64);
#pragma unroll
          for (int f = 0; f < 4; ++f)
#pragma unroll
            for (int r = 0; r < 4; ++r) o1[f][r] *= at[r];
        }
        float psum = 0.f;
#pragma unroll
        for (int s4 = 0; s4 < 4; ++s4) {
          float p0 = exp2_fast(s1[s4 * 4 + 0] - mi1);
          float p1 = exp2_fast(s1[s4 * 4 + 1] - mi1);
          float p2 = exp2_fast(s1[s4 * 4 + 2] - mi1);
          float p3 = exp2_fast(s1[s4 * 4 + 3] - mi1);
          psum += (p0 + p1) + (p2 + p3);
          unsigned lo, hi;
          asm("v_cvt_pk_bf16_f32 %0, %1, %2" : "=v"(lo) : "v"(p0), "v"(p1));
          asm("v_cvt_pk_bf16_f32 %0, %1, %2" : "=v"(hi) : "v"(p2), "v"(p3));
          uint2 packed; packed.x = lo; packed.y = hi;
          pf1[s4] = __builtin_bit_cast(short4_t, packed);
        }
        psum += __shfl_xor(psum, 16, 64);
        psum += __shfl_xor(psum, 32, 64);
        li1 += psum;
      }
    }

    // --- write next-tile V into alternate buffer (all threads) ---
    if (has_next) {
      *(short4_t*)(lvn + vdst) = va0;
      *(short4_t*)(lvn + (vdst ^ 4)) = va1;
      *(short4_t*)(lvn + vdst + 2048) = vb0;
      *(short4_t*)(lvn + (vdst ^ 4) + 2048) = vb1;
    }

    // --- PV: shared vf fragments feed BOTH groups ---
    if (active) {
#pragma unroll
      for (int f = 0; f < 4; ++f) {
        const unsigned short* vr = lvc + (f * 16 + lcol) * 64;
#pragma unroll
        for (int s4 = 0; s4 < 4; ++s4) {
          short4_t vf = *(const short4_t*)(vr + voff[s4]);
          o0[f] = __builtin_amdgcn_mfma_f32_16x16x16bf16_1k(pf0[s4], vf, o0[f], 0, 0, 0);
          o1[f] = __builtin_amdgcn_mfma_f32_16x16x16bf16_1k(pf1[s4], vf, o1[f], 0, 0, 0);
        }
      }
    }

    __syncthreads();
    unsigned short* t;
    t = lkc; lkc = lkn; lkn = t;
    t = lvc; lvc = lvn; lvn = t;
  }

  float lt0[4], lt1[4];
#pragma unroll
  for (int r = 0; r < 4; ++r) {
    lt0[r] = 1.f / __shfl(li0, quad * 4 + r, 64);
    lt1[r] = 1.f / __shfl(li1, quad * 4 + r, 64);
  }
#pragma unroll
  for (int f = 0; f < 4; ++f)
#pragma unroll
    for (int r = 0; r < 4; ++r) {
      int hd = f * 16 + lcol;
      int q0 = q0w + quad * 4 + r;
      int q1 = q0w + 16 + quad * 4 + r;
      ao[((size_t)b * Sq + q0) * (NH * HD) + h * HD + hd] = f2bf(o0[f][r] * lt0[r]);
      ao[((size_t)b * Sq + q1) * (NH * HD) + h * HD + hd] = f2bf(o1[f][r] * lt1[r]);
    }
}

extern "C" void kernel_launch(void* const* d_in, const int* in_sizes, int n_in,
                              void* d_out, int out_size, void* d_ws, size_t ws_size,
                              hipStream_t stream) {
  const float* x = (const float*)d_in[0];
  const float* Wq = (const float*)d_in[1];
  const float* Wk = (const float*)d_in[2];
  const float* Wv = (const float*)d_in[3];
  const float* Wo = (const float*)d_in[4];
  float* out = (float*)d_out;

  char* ws = (char*)d_ws;
  size_t off = 0;
  auto carve = [&](size_t bytes) {
    void* p = ws + off;
    off += (bytes + 255) & ~(size_t)255;
    return p;
  };
  const size_t xe = (size_t)Bz * Sq * Dm;
  const size_t we = (size_t)Dm * Dm;
  unsigned short* xb = (unsigned short*)carve(xe * 2);
  unsigned short* wqT = (unsigned short*)carve(we * 2);
  unsigned short* wkT = (unsigned short*)carve(we * 2);
  unsigned short* wvT = (unsigned short*)carve(we * 2);
  unsigned short* woT = (unsigned short*)carve(we * 2);
  unsigned short* qb = (unsigned short*)carve(xe * 2);
  unsigned short* kb = (unsigned short*)carve(xe * 2);
  unsigned short* vt = (unsigned short*)carve(xe * 2);
  unsigned short* ao = (unsigned short*)carve(xe * 2);
  (void)ws_size;

  cast_x_kernel<<<xe / 4 / 256, 256, 0, stream>>>(x, xb);
  transpose_w_kernel<<<dim3(16, 16, 4), 256, 0, stream>>>(Wq, Wk, Wv, Wo,
                                                          wqT, wkT, wvT, woT);
  gemm_qkv_kernel<<<768, 512, 0, stream>>>(xb, wqT, wkT, wvT, qb, kb, vt);
  attn_kernel<<<dim3(Bz * NH, 16), 256, 0, stream>>>(qb, kb, vt, ao);
  gemm_out_kernel<<<256, 512, 0, stream>>>(ao, woT, out);
}